// Round 17
// baseline (91.306 us; speedup 1.0000x reference)
//
#include <hip/hip_runtime.h>

#define NN 400
#define FF 240
#define CC 32
#define NIN 304   // F + 2C
#define LL 1440
#define NB 250
#define NGROUPS 16

struct Params {
    const float *x, *a, *e0;
    const float *c1_sw, *c1_sb, *c1_aiw, *c1_aib, *c1_ajw, *c1_ajb;
    const float *c1_nw, *c1_nb, *c1_ew, *c1_eb;
    const float *c2_sw, *c2_sb, *c2_aiw, *c2_aib, *c2_ajw, *c2_ajb;
    const float *c2_nw, *c2_nb;
    const float *dw, *db;
    float *out;
    float *P1, *Q1, *P2, *Q2, *x1, *x2, *e1;
    unsigned *bar;     // gcnt[16*16] @0, mcnt @256, grel[16*16] @272 (RMW-only)
};

// ---------------------------------------------------------------------------
// Grid barrier, lessons R4+R5 applied: RMW-only coherence (m20), ONE
// threadfence per block (thread 0, post-syncthreads so all stores are
// already drained to L2), two-level counter tree to avoid single-line
// serialization of 250 atomics.
// ---------------------------------------------------------------------------
__device__ __forceinline__ void gbar(unsigned* bar, int phase) {
    __syncthreads();
    if (threadIdx.x == 0) {
        __threadfence();                       // release: wb local XCD L2
        unsigned* gcnt = bar;                  // 16 counters, stride 16
        unsigned* mcnt = bar + 256;
        unsigned* grel = bar + 272;            // 16 release lines, stride 16
        const int g   = blockIdx.x >> 4;
        const int gsz = min(16, NB - (g << 4));
        const unsigned o = atomicAdd(&gcnt[g * 16], 1u);
        if (o + 1u == (unsigned)(phase * gsz)) {
            const unsigned m = atomicAdd(mcnt, 1u);
            if (m + 1u == (unsigned)(phase * NGROUPS)) {
                #pragma unroll
                for (int g2 = 0; g2 < NGROUPS; ++g2) atomicAdd(&grel[g2 * 16], 1u);
            }
        }
        while (atomicAdd(&grel[g * 16], 0u) < (unsigned)phase)   // RMW spin
            __builtin_amdgcn_s_sleep(8);
        __threadfence();                       // acquire: inv L1 + local L2
    }
    __syncthreads();
}

// ---------------------------------------------------------------------------
// rcf+node body (R16 proven code, smem passed in).
// smem layout (floats): red @0 (18432), part @18432, vA @19456, vB @19760,
// xsA @20064, xsB @20304, eout @20544  -> 21344 total.
// ---------------------------------------------------------------------------
template<bool WRITE_E, bool DO_PQ>
__device__ void rcf_body(const Params& p, int job, float* smem,
                         const float* P, const float* Q, const float* e,
                         const float* sw_tail, const float* aiw, const float* aib,
                         const float* ajw, const float* ajb,
                         const float* ew, const float* eb, float* e_out,
                         const float* xin, const float* nw, const float* nb,
                         const float* sw2, const float* sb2,
                         float* xout, float* Pout, float* Qout) {
    const int base = (job & 7) * 50 + (job >> 3) * 2;   // even, XCD-clustered
    const int t  = threadIdx.x;
    const int pg = t >> 3, l = t & 7, c0 = l * 4;

    float* red  = smem;
    float* part = smem + 18432;
    float* vA   = smem + 19456;
    float* vB   = smem + 19760;
    float* xsA  = smem + 20064;
    float* xsB  = smem + 20304;
    float* eout_lds = smem + 20544;
    float* redn = red;
    float* red2 = red;

    if (t < FF) {
        vA[t] = xin[base * FF + t];
        vB[t] = xin[(base + 1) * FF + t];
    }

    float2 er2[4], ak2[4];
    int kk[4];
    #pragma unroll
    for (int it = 0; it < 4; ++it) {
        const int off = it * 128 + pg;
        kk[it] = (off < NN) ? off : 0;
        er2[it] = *(const float2*)(e + kk[it] * NN + base);
        ak2[it] = *(const float2*)(p.a + kk[it] * NN + base);
    }

    float w1v[4], w2v[4], wiv[4], wjv[4], wev[4];
    *(float4*)w1v = *(const float4*)(sw_tail + c0);
    *(float4*)w2v = *(const float4*)(sw_tail + CC + c0);
    *(float4*)wiv = *(const float4*)(aiw + c0);
    *(float4*)wjv = *(const float4*)(ajw + c0);
    if (WRITE_E) *(float4*)wev = *(const float4*)(ew + c0);
    const float bi = aib[0], bj = ajb[0];
    const float be = WRITE_E ? eb[0] : 0.0f;

    #pragma unroll
    for (int rp = 0; rp < 2; ++rp) {
        const int b = base + rp;
        float Pb[4], Qb[4];
        *(float4*)Pb = *(const float4*)(P + b * CC + c0);
        *(float4*)Qb = *(const float4*)(Q + b * CC + c0);
        float acc_i[4] = {0, 0, 0, 0}, acc_j[4] = {0, 0, 0, 0};
        #pragma unroll
        for (int it = 0; it < 4; ++it) {
            const int off = it * 128 + pg;
            const bool valid = off < NN;
            const int k = kk[it];
            float Qk[4], Pk[4];
            *(float4*)Qk = *(const float4*)(Q + k * CC + c0);
            *(float4*)Pk = *(const float4*)(P + k * CC + c0);
            const float e_f  = e[b * NN + k];
            const float a_bk = p.a[b * NN + k];
            const float e_r  = rp ? er2[it].y : er2[it].x;
            const float a_kb = rp ? ak2[it].y : ak2[it].x;
            float sr[4], sc[4];
            #pragma unroll
            for (int q = 0; q < 4; ++q) {
                sr[q] = fmaxf(Pb[q] + Qk[q] + e_f * w1v[q] + e_r * w2v[q], 0.0f) * a_bk;
                sc[q] = fmaxf(Pk[q] + Qb[q] + e_r * w1v[q] + e_f * w2v[q], 0.0f) * a_kb;
            }
            float d_i = sr[0] * wiv[0] + sr[1] * wiv[1] + sr[2] * wiv[2] + sr[3] * wiv[3];
            float d_j = sc[0] * wjv[0] + sc[1] * wjv[1] + sc[2] * wjv[2] + sc[3] * wjv[3];
            float d_e = WRITE_E ? (sr[0] * wev[0] + sr[1] * wev[1] + sr[2] * wev[2] + sr[3] * wev[3]) : 0.0f;
            #pragma unroll
            for (int m = 1; m < 8; m <<= 1) {
                d_i += __shfl_xor(d_i, m);
                d_j += __shfl_xor(d_j, m);
                if (WRITE_E) d_e += __shfl_xor(d_e, m);
            }
            const float gi = valid ? __fdividef(1.0f, 1.0f + __expf(-(d_i + bi))) : 0.0f;
            const float gj = valid ? __fdividef(1.0f, 1.0f + __expf(-(d_j + bj))) : 0.0f;
            #pragma unroll
            for (int q = 0; q < 4; ++q) {
                acc_i[q] += gi * sr[q];
                acc_j[q] += gj * sc[q];
            }
            if (WRITE_E && l == 0 && valid) eout_lds[rp * NN + k] = d_e + be;
        }
        #pragma unroll
        for (int q = 0; q < 4; ++q) {
            red[((rp * 2 + 0) * 128 + pg) * 36 + c0 + q] = acc_i[q];
            red[((rp * 2 + 1) * 128 + pg) * 36 + c0 + q] = acc_j[q];
        }
    }
    __syncthreads();

    if (WRITE_E && t < 2 * NN) e_out[base * NN + t] = eout_lds[t];

    {   // combined stage-1: set = t>>8 (0=iA 1=jA 2=iB 3=jB)
        const int c = t & 31, sg = (t >> 5) & 7, set = t >> 8;
        float s = 0.0f;
        #pragma unroll
        for (int g2 = sg * 16; g2 < sg * 16 + 16; ++g2)
            s += red[(set * 128 + g2) * 36 + c];
        part[t] = s;
    }
    __syncthreads();
    if (t < 128) {
        const int set = t >> 5, c = t & 31;
        float s = 0.0f;
        #pragma unroll
        for (int sg = 0; sg < 8; ++sg) s += part[set * 256 + sg * 32 + c];
        float* vdst = (set < 2) ? vA : vB;
        vdst[FF + (set & 1) * CC + c] = s;
    }
    __syncthreads();

    {   // node tail, both rows
        const int fg = t % 60, h = t / 60;
        if (t < 960) {
            const int f0 = fg * 4;
            float4 aA = make_float4(0.f, 0.f, 0.f, 0.f);
            float4 aB = make_float4(0.f, 0.f, 0.f, 0.f);
            const int k0 = h * 19;
            #pragma unroll
            for (int k = k0; k < k0 + 19; ++k) {
                const float4 w = *(const float4*)(nw + k * FF + f0);
                const float va = vA[k], vb = vB[k];
                aA.x += va * w.x; aA.y += va * w.y; aA.z += va * w.z; aA.w += va * w.w;
                aB.x += vb * w.x; aB.y += vb * w.y; aB.z += vb * w.z; aB.w += vb * w.w;
            }
            *(float4*)(redn + h * 240 + f0)        = aA;
            *(float4*)(redn + 3840 + h * 240 + f0) = aB;
        }
    }
    __syncthreads();
    if (t < FF) {
        float rA = nb[t], rB = nb[t];
        #pragma unroll
        for (int h = 0; h < 16; ++h) {
            rA += redn[h * 240 + t];
            rB += redn[3840 + h * 240 + t];
        }
        xout[base * FF + t]       = rA;
        xout[(base + 1) * FF + t] = rB;
        xsA[t] = rA;
        xsB[t] = rB;
    }
    if (DO_PQ) {
        __syncthreads();
        const int c = t & 31, isQ = (t >> 5) & 1, g = t >> 6;
        const float* wb = sw2 + (isQ ? FF * CC : 0) + c;
        const float bias = (!isQ && g == 0) ? sb2[c] : 0.0f;
        float accA = bias, accB = bias;
        const int f0 = g * 15;
        #pragma unroll
        for (int f = f0; f < f0 + 15; ++f) {
            const float w = wb[f * CC];
            accA += xsA[f] * w;
            accB += xsB[f] * w;
        }
        red2[g * 64 + (t & 63)]        = accA;
        red2[1024 + g * 64 + (t & 63)] = accB;
        __syncthreads();
        if (t < 128) {
            const int row = t >> 6, slot = t & 63;
            float s = 0.0f;
            #pragma unroll
            for (int g2 = 0; g2 < 16; ++g2) s += red2[row * 1024 + g2 * 64 + slot];
            const int bb = base + row;
            if (slot >= 32) Qout[bb * CC + (slot & 31)] = s;
            else            Pout[bb * CC + slot] = s;
        }
    }
}

// ---------------------------------------------------------------------------
// The mono kernel: pq1 | rcf1+node1+pq2 | rcf2+node2 | dense, 3 grid barriers.
// 250 blocks x 1024 threads, co-resident by construction (<=256 CUs).
// ---------------------------------------------------------------------------
__global__ __launch_bounds__(1024) void xenet_mono2(Params p) {
    __shared__ float smem[21344];   // 85.4 KB, unioned across phases
    const int bid = blockIdx.x;
    const int t   = threadIdx.x;

    // ---- P0: layer-1 P/Q projection (4 rows per working block) ----
    if (bid < 100) {
        const int i0 = bid * 4;
        const int r = t >> 8, tt = t & 255;
        const int c = tt & 31, isQ = (tt >> 5) & 1, g = tt >> 6;
        const float* wb = p.c1_sw + (isQ ? FF * CC : 0) + c;
        float acc = (!isQ && g == 0) ? p.c1_sb[c] : 0.0f;
        const float* xr = p.x + (i0 + r) * FF;
        const int f0 = g * 60;
        #pragma unroll 4
        for (int f = f0; f < f0 + 60; ++f) acc += xr[f] * wb[f * CC];
        smem[r * 256 + g * 64 + (tt & 63)] = acc;
        __syncthreads();
        if (tt < 64) {
            float s = smem[r * 256 + tt] + smem[r * 256 + 64 + tt]
                    + smem[r * 256 + 128 + tt] + smem[r * 256 + 192 + tt];
            const int i = i0 + r;
            if (tt >= 32) p.Q1[i * CC + (tt & 31)] = s;
            else          p.P1[i * CC + tt] = s;
        }
    }
    gbar(p.bar, 1);

    // ---- P1: layer-1 rcf + node + layer-2 P/Q ----
    if (bid < 200)
        rcf_body<true, true>(p, bid, smem, p.P1, p.Q1, p.e0,
            p.c1_sw + 480 * CC, p.c1_aiw, p.c1_aib, p.c1_ajw, p.c1_ajb,
            p.c1_ew, p.c1_eb, p.e1,
            p.x, p.c1_nw, p.c1_nb, p.c2_sw, p.c2_sb, p.x1, p.P2, p.Q2);
    gbar(p.bar, 2);

    // ---- P2: layer-2 rcf + node ----
    if (bid < 200)
        rcf_body<false, false>(p, bid, smem, p.P2, p.Q2, p.e1,
            p.c2_sw + 480 * CC, p.c2_aiw, p.c2_aib, p.c2_ajw, p.c2_ajb,
            nullptr, nullptr, nullptr,
            p.x1, p.c2_nw, p.c2_nb, nullptr, nullptr, p.x2, nullptr, nullptr);
    gbar(p.bar, 3);

    // ---- P3: final dense, 250 jobs = 50 row-groups x 5 l-chunks of 288 ----
    {
        const int ig = bid / 5, lb = bid % 5;
        const int i0 = ig * 8;
        float* xs   = smem;          // 1920
        float* dred = smem + 1920;   // 24*288 = 6912
        for (int idx = t; idx < 8 * FF; idx += 1024) {
            xs[idx] = p.x2[i0 * FF + idx];
        }
        __syncthreads();
        const int fs = t / 288, li = t % 288;
        float acc[8] = {0, 0, 0, 0, 0, 0, 0, 0};
        if (fs < 3) {
            const int f0 = fs * 80;
            const int gl = lb * 288 + li;
            #pragma unroll 4
            for (int f = f0; f < f0 + 80; ++f) {
                const float w = p.dw[f * LL + gl];
                #pragma unroll
                for (int r = 0; r < 8; ++r) acc[r] += xs[r * FF + f] * w;
            }
            #pragma unroll
            for (int r = 0; r < 8; ++r) dred[(fs * 8 + r) * 288 + li] = acc[r];
        }
        __syncthreads();
        if (t < 288) {
            const int gl = lb * 288 + t;
            const float d = p.db[gl];
            #pragma unroll
            for (int r = 0; r < 8; ++r) {
                const float s = dred[r * 288 + t] + dred[(8 + r) * 288 + t]
                              + dred[(16 + r) * 288 + t];
                p.out[(i0 + r) * LL + gl] = d + s;
            }
        }
    }
}

extern "C" void kernel_launch(void* const* d_in, const int* in_sizes, int n_in,
                              void* d_out, int out_size, void* d_ws, size_t ws_size,
                              hipStream_t stream) {
    Params p;
    p.x  = (const float*)d_in[0];
    p.a  = (const float*)d_in[1];
    p.e0 = (const float*)d_in[2];
    p.c1_sw  = (const float*)d_in[3];
    p.c1_sb  = (const float*)d_in[4];
    p.c1_aiw = (const float*)d_in[5];
    p.c1_aib = (const float*)d_in[6];
    p.c1_ajw = (const float*)d_in[7];
    p.c1_ajb = (const float*)d_in[8];
    p.c1_nw  = (const float*)d_in[9];
    p.c1_nb  = (const float*)d_in[10];
    p.c1_ew  = (const float*)d_in[11];
    p.c1_eb  = (const float*)d_in[12];
    p.c2_sw  = (const float*)d_in[13];
    p.c2_sb  = (const float*)d_in[14];
    p.c2_aiw = (const float*)d_in[15];
    p.c2_aib = (const float*)d_in[16];
    p.c2_ajw = (const float*)d_in[17];
    p.c2_ajb = (const float*)d_in[18];
    p.c2_nw  = (const float*)d_in[19];
    p.c2_nb  = (const float*)d_in[20];
    // d_in[21]/d_in[22]: layer-2 edge output is dead code
    p.dw = (const float*)d_in[23];
    p.db = (const float*)d_in[24];
    p.out = (float*)d_out;

    float* ws = (float*)d_ws;
    p.P1 = ws;                 // 12800
    p.Q1 = ws + 12800;         // 12800
    p.P2 = ws + 25600;         // 12800
    p.Q2 = ws + 38400;         // 12800
    p.x1 = ws + 51200;         // 96000
    p.x2 = ws + 147200;        // 96000
    p.e1 = ws + 243200;        // 160000
    p.bar = (unsigned*)(ws + 450000);   // 528 uints of barrier state

    // zero barrier state every call (capture-safe memset node)
    hipMemsetAsync((void*)p.bar, 0, 544 * sizeof(unsigned), stream);

    xenet_mono2<<<NB, 1024, 0, stream>>>(p);
}

// Round 18
// 52.948 us; speedup vs baseline: 1.7245x; 1.7245x over previous
//
#include <hip/hip_runtime.h>

#define NN 400
#define FF 240
#define CC 32
#define NIN 304   // F + 2C
#define LL 1440

// ---------------------------------------------------------------------------
// K1: P/Q projection, 1 row per block. grid = 400 blocks, 256 threads.
// ---------------------------------------------------------------------------
__global__ __launch_bounds__(256) void pq_kernel(
    const float* __restrict__ x, const float* __restrict__ sw,
    const float* __restrict__ sb, float* __restrict__ P, float* __restrict__ Q) {
    const int i   = blockIdx.x;
    const int t   = threadIdx.x;
    const int c   = t & 31;
    const int isQ = (t >> 5) & 1;
    const int g   = t >> 6;            // 0..3, 60 f each
    const float* wb = sw + (isQ ? FF * CC : 0) + c;
    float acc = (!isQ && g == 0) ? sb[c] : 0.0f;
    const float* xr = x + i * FF;
    const int f0 = g * 60;
    #pragma unroll 4
    for (int f = f0; f < f0 + 60; ++f) acc += xr[f] * wb[f * CC];
    __shared__ float red[4][64];
    red[g][t & 63] = acc;
    __syncthreads();
    if (t < 64) {
        const float s = red[0][t] + red[1][t] + red[2][t] + red[3][t];
        if (t >= 32) Q[i * CC + (t & 31)] = s;
        else         P[i * CC + t] = s;
    }
}

// ---------------------------------------------------------------------------
// K2/K3: R16 structure (two sequential row k-loops, combined 3-barrier
// reduction, shared float2 column gathers) + ALL global loads hoisted:
// e_f/a_bk row-direction scalars now pre-loaded alongside er2/ak2, so the
// k-loop is pure compute with ~24 loads in flight up front.
// pg = t>>3 pair-group in [0,128), l = t&7 channel quad.
// red = [4 sets][128 pg][36] ; sets: 0=iA 1=jA 2=iB 3=jB.
// ---------------------------------------------------------------------------
template<bool WRITE_E, bool DO_PQ>
__global__ __launch_bounds__(1024) void rcf_node(
    const float* __restrict__ P, const float* __restrict__ Q,
    const float* __restrict__ e, const float* __restrict__ a,
    const float* __restrict__ sw_tail,   // sw + 480*CC : rows [w1 ; w2]
    const float* __restrict__ aiw, const float* __restrict__ aib,
    const float* __restrict__ ajw, const float* __restrict__ ajb,
    const float* __restrict__ ew, const float* __restrict__ eb,
    float* __restrict__ e_out,
    const float* __restrict__ xin, const float* __restrict__ nw,
    const float* __restrict__ nb,
    const float* __restrict__ sw2, const float* __restrict__ sb2,
    float* __restrict__ xout, float* __restrict__ Pout, float* __restrict__ Qout) {
    const int bid  = blockIdx.x;
    const int base = (bid & 7) * 50 + (bid >> 3) * 2;   // even
    const int t  = threadIdx.x;
    const int pg = t >> 3, l = t & 7, c0 = l * 4;

    __shared__ float red[4 * 128 * 36];   // 73.7 KB (overlaid by redn/red2)
    __shared__ float part[1024];
    __shared__ float vA[304], vB[304], xsA[240], xsB[240];
    __shared__ float eout_lds[2 * NN];
    float* redn = red;
    float* red2 = red;

    if (t < FF) {                 // stage both x-rows early
        vA[t] = xin[base * FF + t];
        vB[t] = xin[(base + 1) * FF + t];
    }

    // hoisted loads: column gathers (shared float2) + row-direction scalars
    float2 er2[4], ak2[4];
    float e_fA[4], e_fB[4], a_bkA[4], a_bkB[4];
    int kk[4];
    #pragma unroll
    for (int it = 0; it < 4; ++it) {
        const int off = it * 128 + pg;
        kk[it] = (off < NN) ? off : 0;
        er2[it]   = *(const float2*)(e + kk[it] * NN + base);
        ak2[it]   = *(const float2*)(a + kk[it] * NN + base);
        e_fA[it]  = e[base * NN + kk[it]];
        e_fB[it]  = e[(base + 1) * NN + kk[it]];
        a_bkA[it] = a[base * NN + kk[it]];
        a_bkB[it] = a[(base + 1) * NN + kk[it]];
    }

    float w1v[4], w2v[4], wiv[4], wjv[4], wev[4];
    *(float4*)w1v = *(const float4*)(sw_tail + c0);
    *(float4*)w2v = *(const float4*)(sw_tail + CC + c0);
    *(float4*)wiv = *(const float4*)(aiw + c0);
    *(float4*)wjv = *(const float4*)(ajw + c0);
    if (WRITE_E) *(float4*)wev = *(const float4*)(ew + c0);
    const float bi = aib[0], bj = ajb[0];
    const float be = WRITE_E ? eb[0] : 0.0f;

    #pragma unroll
    for (int rp = 0; rp < 2; ++rp) {
        const int b = base + rp;

        float Pb[4], Qb[4];
        *(float4*)Pb = *(const float4*)(P + b * CC + c0);
        *(float4*)Qb = *(const float4*)(Q + b * CC + c0);

        float acc_i[4] = {0, 0, 0, 0}, acc_j[4] = {0, 0, 0, 0};
        #pragma unroll
        for (int it = 0; it < 4; ++it) {
            const int off = it * 128 + pg;
            const bool valid = off < NN;
            const int k = kk[it];
            float Qk[4], Pk[4];
            *(float4*)Qk = *(const float4*)(Q + k * CC + c0);
            *(float4*)Pk = *(const float4*)(P + k * CC + c0);
            const float e_f  = rp ? e_fB[it]  : e_fA[it];
            const float a_bk = rp ? a_bkB[it] : a_bkA[it];
            const float e_r  = rp ? er2[it].y : er2[it].x;
            const float a_kb = rp ? ak2[it].y : ak2[it].x;
            float sr[4], sc[4];
            #pragma unroll
            for (int q = 0; q < 4; ++q) {
                sr[q] = fmaxf(Pb[q] + Qk[q] + e_f * w1v[q] + e_r * w2v[q], 0.0f) * a_bk;
                sc[q] = fmaxf(Pk[q] + Qb[q] + e_r * w1v[q] + e_f * w2v[q], 0.0f) * a_kb;
            }
            float d_i = sr[0] * wiv[0] + sr[1] * wiv[1] + sr[2] * wiv[2] + sr[3] * wiv[3];
            float d_j = sc[0] * wjv[0] + sc[1] * wjv[1] + sc[2] * wjv[2] + sc[3] * wjv[3];
            float d_e = WRITE_E ? (sr[0] * wev[0] + sr[1] * wev[1] + sr[2] * wev[2] + sr[3] * wev[3]) : 0.0f;
            #pragma unroll
            for (int m = 1; m < 8; m <<= 1) {
                d_i += __shfl_xor(d_i, m);
                d_j += __shfl_xor(d_j, m);
                if (WRITE_E) d_e += __shfl_xor(d_e, m);
            }
            const float gi = valid ? __fdividef(1.0f, 1.0f + __expf(-(d_i + bi))) : 0.0f;
            const float gj = valid ? __fdividef(1.0f, 1.0f + __expf(-(d_j + bj))) : 0.0f;
            #pragma unroll
            for (int q = 0; q < 4; ++q) {
                acc_i[q] += gi * sr[q];
                acc_j[q] += gj * sc[q];
            }
            if (WRITE_E && l == 0 && valid) eout_lds[rp * NN + k] = d_e + be;
        }
        // publish this row's partials to LDS — NO barrier yet
        #pragma unroll
        for (int q = 0; q < 4; ++q) {
            red[((rp * 2 + 0) * 128 + pg) * 36 + c0 + q] = acc_i[q];
            red[((rp * 2 + 1) * 128 + pg) * 36 + c0 + q] = acc_j[q];
        }
    }
    __syncthreads();   // sync #1

    if (WRITE_E && t < 2 * NN) e_out[base * NN + t] = eout_lds[t];

    {   // combined stage-1: 1024 threads, set = t>>8
        const int c = t & 31, sg = (t >> 5) & 7, set = t >> 8;
        float s = 0.0f;
        #pragma unroll
        for (int g2 = sg * 16; g2 < sg * 16 + 16; ++g2)
            s += red[(set * 128 + g2) * 36 + c];
        part[t] = s;
    }
    __syncthreads();   // sync #2
    if (t < 128) {
        const int set = t >> 5, c = t & 31;
        float s = 0.0f;
        #pragma unroll
        for (int sg = 0; sg < 8; ++sg) s += part[set * 256 + sg * 32 + c];
        float* vdst = (set < 2) ? vA : vB;
        vdst[FF + (set & 1) * CC + c] = s;
    }
    __syncthreads();   // sync #3

    {   // node tail, both rows: nw read once per block
        const int fg = t % 60, h = t / 60;
        if (t < 960) {
            const int f0 = fg * 4;
            float4 aA = make_float4(0.f, 0.f, 0.f, 0.f);
            float4 aB = make_float4(0.f, 0.f, 0.f, 0.f);
            const int k0 = h * 19;
            #pragma unroll
            for (int k = k0; k < k0 + 19; ++k) {
                const float4 w = *(const float4*)(nw + k * FF + f0);
                const float va = vA[k], vb = vB[k];
                aA.x += va * w.x; aA.y += va * w.y; aA.z += va * w.z; aA.w += va * w.w;
                aB.x += vb * w.x; aB.y += vb * w.y; aB.z += vb * w.z; aB.w += vb * w.w;
            }
            *(float4*)(redn + h * 240 + f0)        = aA;
            *(float4*)(redn + 3840 + h * 240 + f0) = aB;
        }
    }
    __syncthreads();
    if (t < FF) {
        float rA = nb[t], rB = nb[t];
        #pragma unroll
        for (int h = 0; h < 16; ++h) {
            rA += redn[h * 240 + t];
            rB += redn[3840 + h * 240 + t];
        }
        xout[base * FF + t]       = rA;
        xout[(base + 1) * FF + t] = rB;
        xsA[t] = rA;
        xsB[t] = rB;
    }
    if (DO_PQ) {
        __syncthreads();
        const int c = t & 31, isQ = (t >> 5) & 1, g = t >> 6;   // g in [0,16)
        const float* wb = sw2 + (isQ ? FF * CC : 0) + c;
        const float bias = (!isQ && g == 0) ? sb2[c] : 0.0f;
        float accA = bias, accB = bias;
        const int f0 = g * 15;
        #pragma unroll
        for (int f = f0; f < f0 + 15; ++f) {
            const float w = wb[f * CC];
            accA += xsA[f] * w;
            accB += xsB[f] * w;
        }
        red2[g * 64 + (t & 63)]        = accA;
        red2[1024 + g * 64 + (t & 63)] = accB;
        __syncthreads();
        if (t < 128) {
            const int row = t >> 6, slot = t & 63;
            float s = 0.0f;
            #pragma unroll
            for (int g2 = 0; g2 < 16; ++g2) s += red2[row * 1024 + g2 * 64 + slot];
            const int bb = base + row;
            if (slot >= 32) Qout[bb * CC + (slot & 31)] = s;
            else            Pout[bb * CC + slot] = s;
        }
    }
}

// ---------------------------------------------------------------------------
// K4: in-block split-K dense, 5 rows/block. grid (80,6) = 480 blocks at
// ~25 KB LDS -> 2 blocks/CU -> ALL co-resident in one round (vs R16's 300
// blocks @ 1/CU = 1.17 rounds), 8 waves/SIMD for the latency-bound dw reads.
// 1024 threads = 4 f-chunks x 256 l-lanes; 60 loads/thread.
// ---------------------------------------------------------------------------
__global__ __launch_bounds__(1024) void dense_kernel(
    const float* __restrict__ x, const float* __restrict__ dw,
    const float* __restrict__ db, float* __restrict__ out) {
    const int i0 = blockIdx.x * 5;
    const int t  = threadIdx.x;
    const int l  = t & 255;          // l-lane
    const int fs = t >> 8;           // f-chunk 0..3
    const int gl = blockIdx.y * 256 + l;
    __shared__ float xs[5 * FF];     // 1200
    __shared__ float red[20 * 256];  // 5120
    for (int idx = t; idx < 5 * FF; idx += 1024) {
        xs[idx] = x[i0 * FF + idx];
    }
    __syncthreads();
    float acc[5] = {0, 0, 0, 0, 0};
    if (gl < LL) {
        const int f0 = fs * 60;
        #pragma unroll 4
        for (int f = f0; f < f0 + 60; ++f) {
            const float w = dw[f * LL + gl];
            #pragma unroll
            for (int r = 0; r < 5; ++r) acc[r] += xs[r * FF + f] * w;
        }
    }
    #pragma unroll
    for (int r = 0; r < 5; ++r) red[(fs * 5 + r) * 256 + l] = acc[r];
    __syncthreads();
    if (t < 256 && gl < LL) {
        const float d = db[gl];
        #pragma unroll
        for (int r = 0; r < 5; ++r) {
            const float s = red[r * 256 + l] + red[(5 + r) * 256 + l]
                          + red[(10 + r) * 256 + l] + red[(15 + r) * 256 + l];
            out[(i0 + r) * LL + gl] = d + s;
        }
    }
}

extern "C" void kernel_launch(void* const* d_in, const int* in_sizes, int n_in,
                              void* d_out, int out_size, void* d_ws, size_t ws_size,
                              hipStream_t stream) {
    const float* x  = (const float*)d_in[0];
    const float* a  = (const float*)d_in[1];
    const float* e0 = (const float*)d_in[2];

    const float* c1_sw  = (const float*)d_in[3];
    const float* c1_sb  = (const float*)d_in[4];
    const float* c1_aiw = (const float*)d_in[5];
    const float* c1_aib = (const float*)d_in[6];
    const float* c1_ajw = (const float*)d_in[7];
    const float* c1_ajb = (const float*)d_in[8];
    const float* c1_nw  = (const float*)d_in[9];
    const float* c1_nb  = (const float*)d_in[10];
    const float* c1_ew  = (const float*)d_in[11];
    const float* c1_eb  = (const float*)d_in[12];

    const float* c2_sw  = (const float*)d_in[13];
    const float* c2_sb  = (const float*)d_in[14];
    const float* c2_aiw = (const float*)d_in[15];
    const float* c2_aib = (const float*)d_in[16];
    const float* c2_ajw = (const float*)d_in[17];
    const float* c2_ajb = (const float*)d_in[18];
    const float* c2_nw  = (const float*)d_in[19];
    const float* c2_nb  = (const float*)d_in[20];
    // d_in[21]/d_in[22] (c2_ew/c2_eb): layer-2 edge output is dead code
    const float* dw = (const float*)d_in[23];
    const float* db = (const float*)d_in[24];

    float* ws = (float*)d_ws;
    float* P1 = ws;                 // 12800
    float* Q1 = ws + 12800;         // 12800
    float* P2 = ws + 25600;         // 12800
    float* Q2 = ws + 38400;         // 12800
    float* x1 = ws + 51200;         // 96000
    float* x2 = ws + 147200;        // 96000
    float* e1 = ws + 243200;        // 160000

    float* out = (float*)d_out;

    // K1: layer-1 P/Q projection
    pq_kernel<<<NN, 256, 0, stream>>>(x, c1_sw, c1_sb, P1, Q1);

    // K2: layer-1 rcf + node model + layer-2 P/Q
    rcf_node<true, true><<<NN / 2, 1024, 0, stream>>>(
        P1, Q1, e0, a, c1_sw + 480 * CC,
        c1_aiw, c1_aib, c1_ajw, c1_ajb, c1_ew, c1_eb, e1,
        x, c1_nw, c1_nb, c2_sw, c2_sb, x1, P2, Q2);

    // K3: layer-2 rcf + node model (no e_out, no next PQ)
    rcf_node<false, false><<<NN / 2, 1024, 0, stream>>>(
        P2, Q2, e1, a, c2_sw + 480 * CC,
        c2_aiw, c2_aib, c2_ajw, c2_ajb, nullptr, nullptr, nullptr,
        x1, c2_nw, c2_nb, nullptr, nullptr, x2, nullptr, nullptr);

    // K4: final dense (5 rows/block, fully co-resident)
    dense_kernel<<<dim3(NN / 5, 6), 1024, 0, stream>>>(x2, dw, db, out);
}